// Round 4
// baseline (111.581 us; speedup 1.0000x reference)
//
#include <hip/hip_runtime.h>
#include <math.h>

#define NH 64
#define NG 32
#define LROW 68   // y-tile row stride in dwords: 272B = 17*16B -> rows 16B-aligned, (4j+lane)%32 conflict-free

// One wave (64 lanes) per catchment s; lane = hidden index h. 1000-step recurrence,
// chunked 64 t at a time:
//  phase A: lane j computes per-step scalars {relu(Ta),Ps,Pl,E} for step t0+j (inline
//           poly acos), stashes them to LDS with one ds_write_b128
//  phase B: 64 serial steps (fully unrolled); per-step scalars come back as ONE
//           same-address ds_read_b128 broadcast (VGPR result -> no SGPR hazards,
//           schedulable far ahead). Step j writes y-contrib to yb[j*LROW+lane].
//           Interleaved: every 4th step also does one b128 read + adds of the
//           PREVIOUS chunk's y-row (fills dependency-stall slots).
//  No __syncthreads anywhere: single-wave block, DS pipe is in-order per wave.
__global__ __launch_bounds__(64) void waternet_kernel(
    const float* __restrict__ x,   // [nt, ns, 4] fp32: P,E,T1,T2
    const float* __restrict__ xc,  // [ns, NG]
    const float* __restrict__ W3,  // [4*NH, NG]
    const float* __restrict__ b3,  // [4*NH]
    float* __restrict__ out,       // [nt, ns]
    int nt, int ns)
{
    // XCD-contiguous catchment map (verified R3: FETCH 64->8.3 MB, WRITE 32->4 MB)
    const int b    = blockIdx.x;
    const int s    = (b & 7) * (ns >> 3) + (b >> 3);
    const int lane = threadIdx.x;           // 0..63 == h

    __shared__ float yb[2][NH * LROW];      // double-buffered y-contrib tile [t][h]
    __shared__ float scal[NH * 4];          // per-step scalars {Tr,Ps,Pl,E}

    // ---- static gates: w = xc[s,:] @ W3^T + b3 (coalesced float4 row loads) ----
    float wq[4];
    #pragma unroll
    for (int q = 0; q < 4; ++q) {
        const float4* row = reinterpret_cast<const float4*>(W3 + (size_t)(q * NH + lane) * NG);
        const float4* xr  = reinterpret_cast<const float4*>(xc + (size_t)s * NG);
        float a = 0.f;
        #pragma unroll
        for (int g = 0; g < NG / 4; ++g) {
            const float4 w  = row[g];
            const float4 xv = xr[g];
            a = fmaf(w.x, xv.x, a); a = fmaf(w.y, xv.y, a);
            a = fmaf(w.z, xv.z, a); a = fmaf(w.w, xv.w, a);
        }
        wq[q] = a + b3[q * NH + lane];
    }
    const float gm = expf(wq[0]) + 1.0f;               // melt gate (>0)
    const float ge = 1.0f / (1.0f + expf(-wq[1]));     // ET gate
    const float go = 1.0f / (1.0f + expf(-wq[2]));     // outflow gate
    float mx = wq[3];
    #pragma unroll
    for (int o = 32; o; o >>= 1) mx = fmaxf(mx, __shfl_xor(mx, o, 64));
    const float ex = expf(wq[3] - mx);
    float smx = ex;
    #pragma unroll
    for (int o = 32; o; o >>= 1) smx += __shfl_xor(smx, o, 64);
    const float ga = ex / smx;                         // softmax over h
    const float gq = go * ga;                          // y contrib   = Hn * gq
    const float gk = 1.0f - go;                        // H carryover = Hn * gk

    float S = 0.f, H = 0.f;
    const int nfull = nt / NH;
    const int tail  = nt - nfull * NH;

    // prefetch chunk 0's forcing (lane j -> timestep j)
    int tp = min(lane, nt - 1);
    float4 f = *reinterpret_cast<const float4*>(x + ((size_t)tp * ns + s) * 4);

    // phase A body: forcing -> {Tr,Ps,Pl,E}, stash to scal[lane*4]
    #define PHASE_A() { \
        const float P = f.x, E = f.y, T1 = f.z, T2 = f.w; \
        const float Ta  = 0.5f * (T1 + T2); \
        const float arg = fminf(1.f, fmaxf(-1.f, (T1 + T2) / (T2 - T1))); \
        const float aa  = fabsf(arg); \
        float p = fmaf(aa, -0.0012624911f, 0.0066700901f); \
        p = fmaf(aa, p, -0.0170881256f); p = fmaf(aa, p, 0.0308918810f); \
        p = fmaf(aa, p, -0.0501743046f); p = fmaf(aa, p, 0.0889789874f); \
        p = fmaf(aa, p, -0.2145988016f); p = fmaf(aa, p, 1.5707963050f); \
        const float rr0 = sqrtf(1.f - aa) * p;                  /* acos(|arg|) */ \
        const float ac  = (arg >= 0.f) ? rr0 : (3.14159265358979f - rr0); \
        const float rr  = 1.f - ac * (1.0f / 3.1415f);          /* module's PI */ \
        const float rP  = (T1 >= 0.f) ? 1.f : ((T2 <= 0.f) ? 0.f : rr); \
        float4 st; st.x = fmaxf(Ta, 0.f); st.y = (1.f - rP) * P; \
        st.z = rP * P;  st.w = E; \
        *reinterpret_cast<float4*>(&scal[lane * 4]) = st; \
    }

    // one recurrence step from broadcast scalars sc = {Tr,Ps,Pl,E}
    #define STEP_BODY(sc, YB, J) { \
        const float M   = sc.x * gm;                     /* relu(Ta*gm) = gm*relu(Ta) */ \
        const float Sm  = fminf(S, M);                   /* snowmelt */ \
        const float tmp = fmaf(-sc.w, ge, sc.z);         /* Pl - E*ge */ \
        const float Hn  = fmaxf(H + Sm + tmp, 0.f); \
        S = (S + sc.y) - Sm; \
        H = Hn * gk; \
        (YB)[(J) * LROW + lane] = Hn * gq; \
    }

    for (int c = 0; c < nfull; ++c) {
        PHASE_A();

        // prefetch next chunk's gather (hidden under phase B)
        tp = min((c + 1) * NH + lane, nt - 1);
        const float4 fn = *reinterpret_cast<const float4*>(x + ((size_t)tp * ns + s) * 4);

        float*       ybw = yb[c & 1];
        const float* ybr = yb[(c & 1) ^ 1];
        float z0 = 0.f, z1 = 0.f, z2 = 0.f, z3 = 0.f;

        #pragma unroll
        for (int j = 0; j < NH; ++j) {
            const float4 sc = *reinterpret_cast<const float4*>(&scal[j * 4]); // broadcast
            STEP_BODY(sc, ybw, j)
            if ((j & 3) == 1) {    // interleaved phase C of chunk c-1 (garbage at c==0, unstored)
                const float4 v = *reinterpret_cast<const float4*>(&ybr[lane * LROW + (j >> 2) * 4]);
                z0 += v.x; z1 += v.y; z2 += v.z; z3 += v.w;
            }
        }
        if (c > 0)
            out[(size_t)((c - 1) * NH + lane) * ns + s] = (z0 + z1) + (z2 + z3);
        f = fn;
    }

    // phase C for the last full chunk
    if (nfull > 0) {
        const float* row = &yb[(nfull - 1) & 1][lane * LROW];
        float z0 = 0.f, z1 = 0.f, z2 = 0.f, z3 = 0.f;
        #pragma unroll
        for (int g = 0; g < NH / 4; ++g) {
            const float4 v = *reinterpret_cast<const float4*>(&row[g * 4]);
            z0 += v.x; z1 += v.y; z2 += v.z; z3 += v.w;
        }
        out[(size_t)((nfull - 1) * NH + lane) * ns + s] = (z0 + z1) + (z2 + z3);
    }

    // tail chunk (nt % 64 steps)
    if (tail > 0) {
        PHASE_A();
        float* ybw = yb[nfull & 1];
        for (int j = 0; j < tail; ++j) {
            const float4 sc = *reinterpret_cast<const float4*>(&scal[j * 4]);
            STEP_BODY(sc, ybw, j)
        }
        if (lane < tail) {
            const float* row = &ybw[lane * LROW];
            float z0 = 0.f, z1 = 0.f, z2 = 0.f, z3 = 0.f;
            #pragma unroll
            for (int g = 0; g < NH / 4; ++g) {
                const float4 v = *reinterpret_cast<const float4*>(&row[g * 4]);
                z0 += v.x; z1 += v.y; z2 += v.z; z3 += v.w;
            }
            out[(size_t)(nfull * NH + lane) * ns + s] = (z0 + z1) + (z2 + z3);
        }
    }
    #undef PHASE_A
    #undef STEP_BODY
}

extern "C" void kernel_launch(void* const* d_in, const int* in_sizes, int n_in,
                              void* d_out, int out_size, void* d_ws, size_t ws_size,
                              hipStream_t stream) {
    const float* x  = (const float*)d_in[0];
    const float* xc = (const float*)d_in[1];
    const float* W3 = (const float*)d_in[2];
    const float* b3 = (const float*)d_in[3];
    float* out = (float*)d_out;

    const int nh = in_sizes[3] / 4;            // 64
    const int ng = in_sizes[2] / (4 * nh);     // 32
    const int ns = in_sizes[1] / ng;           // 1024
    const int nt = in_sizes[0] / (ns * 4);     // 1000

    waternet_kernel<<<dim3(ns), dim3(64), 0, stream>>>(x, xc, W3, b3, out, nt, ns);
}

// Round 5
// 109.190 us; speedup vs baseline: 1.0219x; 1.0219x over previous
//
#include <hip/hip_runtime.h>
#include <math.h>

#define NH 64
#define NG 32
#define YROW 68   // y-tile row stride in dwords: rows 16B-aligned for b128 phase-C reads

// One wave (64 lanes) per catchment s; lane = hidden index h. 1000-step recurrence,
// chunked 64 t at a time:
//  phase A: lane j computes per-step scalars {relu(Ta),Ps,Pl,E} for step t0+j (poly acos),
//           one ds_write_b128 to scal[]
//  phase B: 8 batches of 8 steps. Batch head: 8 broadcast ds_read_b128 (one waitcnt per
//           8 steps -> LDS latency off the serial chain) + per-lane M=Tr*gm, w=Pl-E*ge.
//           Then 8 pure-VALU steps (9 VALU + 1 ds_write y-contrib each).
//  phase C: lane t row-sums its timestep's 64 contributions (16x ds_read_b128).
// No __syncthreads: single-wave block, DS pipe is in-order per wave -> phase A writes
// visible to phase B reads, phase B writes visible to phase C reads, chunk c+1 writes
// ordered after chunk c reads (no WAR) -> single y buffer suffices.
__global__ __launch_bounds__(64) void waternet_kernel(
    const float* __restrict__ x,   // [nt, ns, 4] fp32: P,E,T1,T2
    const float* __restrict__ xc,  // [ns, NG]
    const float* __restrict__ W3,  // [4*NH, NG]
    const float* __restrict__ b3,  // [4*NH]
    float* __restrict__ out,       // [nt, ns]
    int nt, int ns)
{
    // XCD-contiguous catchment map (verified R3: FETCH 64->8.3 MB, WRITE 32->4 MB)
    const int b    = blockIdx.x;
    const int s    = (b & 7) * (ns >> 3) + (b >> 3);
    const int lane = threadIdx.x;           // 0..63 == h

    __shared__ float ytile[NH * YROW];      // 17.4 KB
    __shared__ float scal[NH * 4];          // per-step scalars {Tr,Ps,Pl,E}

    // ---- static gates: w = xc[s,:] @ W3^T + b3 (coalesced float4 row loads) ----
    float wq[4];
    #pragma unroll
    for (int q = 0; q < 4; ++q) {
        const float4* row = reinterpret_cast<const float4*>(W3 + (size_t)(q * NH + lane) * NG);
        const float4* xr  = reinterpret_cast<const float4*>(xc + (size_t)s * NG);
        float a = 0.f;
        #pragma unroll
        for (int g = 0; g < NG / 4; ++g) {
            const float4 w  = row[g];
            const float4 xv = xr[g];
            a = fmaf(w.x, xv.x, a); a = fmaf(w.y, xv.y, a);
            a = fmaf(w.z, xv.z, a); a = fmaf(w.w, xv.w, a);
        }
        wq[q] = a + b3[q * NH + lane];
    }
    const float gm = expf(wq[0]) + 1.0f;               // melt gate (>0)
    const float ge = 1.0f / (1.0f + expf(-wq[1]));     // ET gate
    const float go = 1.0f / (1.0f + expf(-wq[2]));     // outflow gate
    float mx = wq[3];
    #pragma unroll
    for (int o = 32; o; o >>= 1) mx = fmaxf(mx, __shfl_xor(mx, o, 64));
    const float ex = expf(wq[3] - mx);
    float smx = ex;
    #pragma unroll
    for (int o = 32; o; o >>= 1) smx += __shfl_xor(smx, o, 64);
    const float ga = ex / smx;                         // softmax over h
    const float gq = go * ga;                          // y contrib   = Hn * gq
    const float gk = 1.0f - go;                        // H carryover = Hn * gk

    float S = 0.f, H = 0.f;
    const int nfull = nt / NH;          // 15 full chunks (nt=1000)
    const int tail  = nt - nfull * NH;  // 40

    // prefetch chunk 0's forcing (lane j -> timestep j)
    int tp = min(lane, nt - 1);
    float4 f = *reinterpret_cast<const float4*>(x + ((size_t)tp * ns + s) * 4);

    // phase A: forcing -> {Tr,Ps,Pl,E}, stash to scal[lane*4]
    #define PHASE_A() { \
        const float P = f.x, E = f.y, T1 = f.z, T2 = f.w; \
        const float Ta  = 0.5f * (T1 + T2); \
        const float arg = fminf(1.f, fmaxf(-1.f, (T1 + T2) / (T2 - T1))); \
        const float aa  = fabsf(arg); \
        float p = fmaf(aa, -0.0012624911f, 0.0066700901f); \
        p = fmaf(aa, p, -0.0170881256f); p = fmaf(aa, p, 0.0308918810f); \
        p = fmaf(aa, p, -0.0501743046f); p = fmaf(aa, p, 0.0889789874f); \
        p = fmaf(aa, p, -0.2145988016f); p = fmaf(aa, p, 1.5707963050f); \
        const float rr0 = sqrtf(1.f - aa) * p;                  /* acos(|arg|) */ \
        const float ac  = (arg >= 0.f) ? rr0 : (3.14159265358979f - rr0); \
        const float rr  = 1.f - ac * (1.0f / 3.1415f);          /* module's PI */ \
        const float rP  = (T1 >= 0.f) ? 1.f : ((T2 <= 0.f) ? 0.f : rr); \
        float4 st; st.x = fmaxf(Ta, 0.f); st.y = (1.f - rP) * P; \
        st.z = rP * P;  st.w = E; \
        *reinterpret_cast<float4*>(&scal[lane * 4]) = st; \
    }

    // one batch of 8 steps starting at local step j0 (j0 compile-time-constant multiple of 8)
    #define BATCH8(j0) { \
        float4 sc[8]; float M[8], w[8]; \
        _Pragma("unroll") \
        for (int k = 0; k < 8; ++k) \
            sc[k] = *reinterpret_cast<const float4*>(&scal[((j0) + k) * 4]); /* broadcast */ \
        _Pragma("unroll") \
        for (int k = 0; k < 8; ++k) { M[k] = sc[k].x * gm; w[k] = fmaf(-sc[k].w, ge, sc[k].z); } \
        _Pragma("unroll") \
        for (int k = 0; k < 8; ++k) { \
            const float u  = S - M[k]; \
            const float um = fmaxf(u, 0.f);        /* max(S-M,0) */ \
            const float Sm = S - um;               /* = min(S,M) */ \
            S = um + sc[k].y;                      /* S' = max(S-M,0)+Ps */ \
            const float a  = Sm + w[k]; \
            const float Hn = fmaxf(H + a, 0.f); \
            H = Hn * gk; \
            ytile[((j0) + k) * YROW + lane] = Hn * gq; \
        } \
    }

    #pragma unroll 1
    for (int c = 0; c < nfull; ++c) {
        PHASE_A();

        // prefetch next chunk's gather (hidden under phase B)
        tp = min((c + 1) * NH + lane, nt - 1);
        const float4 fn = *reinterpret_cast<const float4*>(x + ((size_t)tp * ns + s) * 4);

        #pragma unroll
        for (int bb = 0; bb < NH / 8; ++bb) BATCH8(bb * 8)

        // phase C: lane t sums its timestep's row
        {
            const float* row = &ytile[lane * YROW];
            float z0 = 0.f, z1 = 0.f, z2 = 0.f, z3 = 0.f;
            #pragma unroll
            for (int g = 0; g < NH / 4; ++g) {
                const float4 v = *reinterpret_cast<const float4*>(&row[g * 4]);
                z0 += v.x; z1 += v.y; z2 += v.z; z3 += v.w;
            }
            out[(size_t)(c * NH + lane) * ns + s] = (z0 + z1) + (z2 + z3);
        }
        f = fn;
    }

    // tail chunk (40 steps = 5 batches for nt=1000; generic remainder handled)
    if (tail > 0) {
        PHASE_A();
        const int nb = tail / 8;
        for (int bb = 0; bb < nb; ++bb) BATCH8(bb * 8)
        for (int j = nb * 8; j < tail; ++j) {          // remainder (0 for nt=1000)
            const float4 sc = *reinterpret_cast<const float4*>(&scal[j * 4]);
            const float M  = sc.x * gm;
            const float w  = fmaf(-sc.w, ge, sc.z);
            const float um = fmaxf(S - M, 0.f);
            const float Sm = S - um;
            S = um + sc.y;
            const float Hn = fmaxf(H + Sm + w, 0.f);
            H = Hn * gk;
            ytile[j * YROW + lane] = Hn * gq;
        }
        if (lane < tail) {
            const float* row = &ytile[lane * YROW];
            float z0 = 0.f, z1 = 0.f, z2 = 0.f, z3 = 0.f;
            #pragma unroll
            for (int g = 0; g < NH / 4; ++g) {
                const float4 v = *reinterpret_cast<const float4*>(&row[g * 4]);
                z0 += v.x; z1 += v.y; z2 += v.z; z3 += v.w;
            }
            out[(size_t)(nfull * NH + lane) * ns + s] = (z0 + z1) + (z2 + z3);
        }
    }
    #undef PHASE_A
    #undef BATCH8
}

extern "C" void kernel_launch(void* const* d_in, const int* in_sizes, int n_in,
                              void* d_out, int out_size, void* d_ws, size_t ws_size,
                              hipStream_t stream) {
    const float* x  = (const float*)d_in[0];
    const float* xc = (const float*)d_in[1];
    const float* W3 = (const float*)d_in[2];
    const float* b3 = (const float*)d_in[3];
    float* out = (float*)d_out;

    const int nh = in_sizes[3] / 4;            // 64
    const int ng = in_sizes[2] / (4 * nh);     // 32
    const int ns = in_sizes[1] / ng;           // 1024
    const int nt = in_sizes[0] / (ns * 4);     // 1000

    waternet_kernel<<<dim3(ns), dim3(64), 0, stream>>>(x, xc, W3, b3, out, nt, ns);
}

// Round 6
// 106.320 us; speedup vs baseline: 1.0495x; 1.0270x over previous
//
#include <hip/hip_runtime.h>
#include <math.h>

#define NH 64
#define NG 32
#define YROW 65   // y-tile row stride (dwords): write banks (j+l)%32, read banks (l+g)%32 -> 2-way, free

// One wave (64 lanes) per catchment s; lane = hidden index h. 1000-step recurrence,
// chunked 64 t at a time, 8 batches of 8 steps per chunk.
// Software-pipelined: batch bb+1's 8 broadcast ds_read_b128 are issued BEFORE batch bb's
// VALU (DS latency hidden under compute). Phase-C reduction of the PREVIOUS chunk's
// y-tile is interleaved 8 b32 reads/batch (conflict-free, fills issue slots).
// No __syncthreads: single-wave block, DS pipe is in-order per wave.
__global__ __launch_bounds__(64) void waternet_kernel(
    const float* __restrict__ x,   // [nt, ns, 4] fp32: P,E,T1,T2
    const float* __restrict__ xc,  // [ns, NG]
    const float* __restrict__ W3,  // [4*NH, NG]
    const float* __restrict__ b3,  // [4*NH]
    float* __restrict__ out,       // [nt, ns]
    int nt, int ns)
{
    // XCD-contiguous catchment map (verified R3: FETCH 64->8.3 MB, WRITE 32->4 MB)
    const int b    = blockIdx.x;
    const int s    = (b & 7) * (ns >> 3) + (b >> 3);
    const int lane = threadIdx.x;           // 0..63 == h

    __shared__ float ytile[2][NH * YROW];   // double-buffered y-contrib tile [t][h]
    __shared__ float scal[NH * 4];          // per-step scalars {Tr,Ps,Pl,E}

    // ---- static gates: w = xc[s,:] @ W3^T + b3 ----
    float wq[4];
    #pragma unroll
    for (int q = 0; q < 4; ++q) {
        const float4* row = reinterpret_cast<const float4*>(W3 + (size_t)(q * NH + lane) * NG);
        const float4* xr  = reinterpret_cast<const float4*>(xc + (size_t)s * NG);
        float a = 0.f;
        #pragma unroll
        for (int g = 0; g < NG / 4; ++g) {
            const float4 w  = row[g];
            const float4 xv = xr[g];
            a = fmaf(w.x, xv.x, a); a = fmaf(w.y, xv.y, a);
            a = fmaf(w.z, xv.z, a); a = fmaf(w.w, xv.w, a);
        }
        wq[q] = a + b3[q * NH + lane];
    }
    const float gm = expf(wq[0]) + 1.0f;               // melt gate (>0)
    const float ge = 1.0f / (1.0f + expf(-wq[1]));     // ET gate
    const float go = 1.0f / (1.0f + expf(-wq[2]));     // outflow gate
    float mx = wq[3];
    #pragma unroll
    for (int o = 32; o; o >>= 1) mx = fmaxf(mx, __shfl_xor(mx, o, 64));
    const float ex = expf(wq[3] - mx);
    float smx = ex;
    #pragma unroll
    for (int o = 32; o; o >>= 1) smx += __shfl_xor(smx, o, 64);
    const float ga = ex / smx;                         // softmax over h
    const float gq = go * ga;                          // y contrib   = Hn * gq
    const float gk = 1.0f - go;                        // H carryover = Hn * gk

    float S = 0.f, H = 0.f;
    const int nfull = nt / NH;          // 15 for nt=1000
    const int tail  = nt - nfull * NH;  // 40

    // prefetch chunk 0's forcing (lane j -> timestep j)
    int tp = min(lane, nt - 1);
    float4 f = *reinterpret_cast<const float4*>(x + ((size_t)tp * ns + s) * 4);

    // phase A: forcing -> {Tr,Ps,Pl,E}, stash to scal[lane*4] (one ds_write_b128)
    #define PHASE_A() { \
        const float P = f.x, E = f.y, T1 = f.z, T2 = f.w; \
        const float Ta  = 0.5f * (T1 + T2); \
        const float arg = fminf(1.f, fmaxf(-1.f, (T1 + T2) / (T2 - T1))); \
        const float aa  = fabsf(arg); \
        float p = fmaf(aa, -0.0012624911f, 0.0066700901f); \
        p = fmaf(aa, p, -0.0170881256f); p = fmaf(aa, p, 0.0308918810f); \
        p = fmaf(aa, p, -0.0501743046f); p = fmaf(aa, p, 0.0889789874f); \
        p = fmaf(aa, p, -0.2145988016f); p = fmaf(aa, p, 1.5707963050f); \
        const float rr0 = sqrtf(1.f - aa) * p;                  /* acos(|arg|) */ \
        const float ac  = (arg >= 0.f) ? rr0 : (3.14159265358979f - rr0); \
        const float rr  = 1.f - ac * (1.0f / 3.1415f);          /* module's PI */ \
        const float rP  = (T1 >= 0.f) ? 1.f : ((T2 <= 0.f) ? 0.f : rr); \
        float4 st; st.x = fmaxf(Ta, 0.f); st.y = (1.f - rP) * P; \
        st.z = rP * P;  st.w = E; \
        *reinterpret_cast<float4*>(&scal[lane * 4]) = st; \
    }

    #define LOAD8(dst, j0) { \
        _Pragma("unroll") \
        for (int k = 0; k < 8; ++k) \
            dst[k] = *reinterpret_cast<const float4*>(&scal[((j0) + k) * 4]); \
    }

    #pragma unroll 1
    for (int c = 0; c < nfull; ++c) {
        PHASE_A();

        // prefetch next chunk's forcing (hidden under this chunk's batches)
        tp = min((c + 1) * NH + lane, nt - 1);
        const float4 fn = *reinterpret_cast<const float4*>(x + ((size_t)tp * ns + s) * 4);

        float*       ybw = ytile[c & 1];
        const float* ybr = ytile[(c & 1) ^ 1];
        float z0 = 0.f, z1 = 0.f;

        float4 sc[8];
        LOAD8(sc, 0)                       // batch 0 (one exposed read latency per chunk)

        #pragma unroll
        for (int bb = 0; bb < NH / 8; ++bb) {
            // pipeline: issue next batch's broadcast reads before this batch's VALU
            float4 scn[8];
            if (bb < NH / 8 - 1) LOAD8(scn, (bb + 1) * 8)

            // interleaved phase C of chunk c-1: 8 conflict-free b32 reads (latency
            // hidden under the step VALU; garbage for c==0, discarded)
            float pc[8];
            #pragma unroll
            for (int k = 0; k < 8; ++k) pc[k] = ybr[lane * YROW + bb * 8 + k];

            float M[8], w[8];
            #pragma unroll
            for (int k = 0; k < 8; ++k) {
                M[k] = sc[k].x * gm;                   // relu(Ta*gm) = gm*relu(Ta), gm>0
                w[k] = fmaf(-sc[k].w, ge, sc[k].z);    // Pl - E*ge
            }
            #pragma unroll
            for (int k = 0; k < 8; ++k) {
                const float Sm = fminf(S, M[k]);           // snowmelt
                S = (S - Sm) + sc[k].y;                    // S' = S - Sm + Ps
                const float Hn = fmaxf((H + Sm) + w[k], 0.f);
                H  = Hn * gk;
                ybw[(bb * 8 + k) * YROW + lane] = Hn * gq; // y contribution
            }
            z0 += (pc[0] + pc[1]) + (pc[2] + pc[3]);
            z1 += (pc[4] + pc[5]) + (pc[6] + pc[7]);

            #pragma unroll
            for (int k = 0; k < 8; ++k) sc[k] = scn[k];    // register rename, no moves
        }

        if (c > 0)
            out[(size_t)((c - 1) * NH + lane) * ns + s] = z0 + z1;
        f = fn;
    }

    // phase C for the last full chunk (standalone, conflict-free b32 reads)
    if (nfull > 0) {
        const float* row = &ytile[(nfull - 1) & 1][lane * YROW];
        float z0 = 0.f, z1 = 0.f;
        #pragma unroll
        for (int g = 0; g < NH; g += 8) {
            z0 += ((row[g+0] + row[g+1]) + (row[g+2] + row[g+3]));
            z1 += ((row[g+4] + row[g+5]) + (row[g+6] + row[g+7]));
        }
        out[(size_t)((nfull - 1) * NH + lane) * ns + s] = z0 + z1;
    }

    // tail chunk (40 steps for nt=1000)
    if (tail > 0) {
        PHASE_A();
        float* ybw = ytile[nfull & 1];
        const int nb = tail / 8;
        for (int bb = 0; bb < nb; ++bb) {
            float4 sc[8];
            LOAD8(sc, bb * 8)
            #pragma unroll
            for (int k = 0; k < 8; ++k) {
                const float M  = sc[k].x * gm;
                const float w  = fmaf(-sc[k].w, ge, sc[k].z);
                const float Sm = fminf(S, M);
                S = (S - Sm) + sc[k].y;
                const float Hn = fmaxf((H + Sm) + w, 0.f);
                H  = Hn * gk;
                ybw[(bb * 8 + k) * YROW + lane] = Hn * gq;
            }
        }
        for (int j = nb * 8; j < tail; ++j) {          // remainder (0 for nt=1000)
            const float4 sc = *reinterpret_cast<const float4*>(&scal[j * 4]);
            const float M  = sc.x * gm;
            const float w  = fmaf(-sc.w, ge, sc.z);
            const float Sm = fminf(S, M);
            S = (S - Sm) + sc.y;
            const float Hn = fmaxf((H + Sm) + w, 0.f);
            H  = Hn * gk;
            ybw[j * YROW + lane] = Hn * gq;
        }
        if (lane < tail) {
            const float* row = &ybw[lane * YROW];
            float z0 = 0.f, z1 = 0.f;
            #pragma unroll
            for (int g = 0; g < NH; g += 8) {
                z0 += ((row[g+0] + row[g+1]) + (row[g+2] + row[g+3]));
                z1 += ((row[g+4] + row[g+5]) + (row[g+6] + row[g+7]));
            }
            out[(size_t)(nfull * NH + lane) * ns + s] = z0 + z1;
        }
    }
    #undef PHASE_A
    #undef LOAD8
}

extern "C" void kernel_launch(void* const* d_in, const int* in_sizes, int n_in,
                              void* d_out, int out_size, void* d_ws, size_t ws_size,
                              hipStream_t stream) {
    const float* x  = (const float*)d_in[0];
    const float* xc = (const float*)d_in[1];
    const float* W3 = (const float*)d_in[2];
    const float* b3 = (const float*)d_in[3];
    float* out = (float*)d_out;

    const int nh = in_sizes[3] / 4;            // 64
    const int ng = in_sizes[2] / (4 * nh);     // 32
    const int ns = in_sizes[1] / ng;           // 1024
    const int nt = in_sizes[0] / (ns * 4);     // 1000

    waternet_kernel<<<dim3(ns), dim3(64), 0, stream>>>(x, xc, W3, b3, out, nt, ns);
}

// Round 7
// 101.663 us; speedup vs baseline: 1.0976x; 1.0458x over previous
//
#include <hip/hip_runtime.h>
#include <math.h>

#define NH 64
#define NG 32
#define YROW 68   // ytile [h][t] row stride (dwords): 16B-aligned rows for b128 writes

// 2 waves per block, one catchment per block (2048 waves total = 2/SIMD).
// Wave 0 (critical): the 1000-step recurrence only. Per step: one broadcast
//   ds_read_b128 of {Tr,Ps,Pl,E} + 8 VALU + (amortized) one ds_write_b128 of
//   4 steps' Hn into ytile[h][t]. H-recurrence folded: Hc' = max(fma(gk,Hc,t),0).
// Wave 1 (helper): phase A (x prefetch + transform -> scal for chunk c+1),
//   phase C (Y[t] = sum_h gq[h]*Hn[t,h] for chunk c-1, 4 accumulators), out store.
// One __syncthreads per chunk; scal/ytile double-buffered.
__global__ __launch_bounds__(128) void waternet_kernel(
    const float* __restrict__ x,   // [nt, ns, 4] fp32: P,E,T1,T2
    const float* __restrict__ xc,  // [ns, NG]
    const float* __restrict__ W3,  // [4*NH, NG]
    const float* __restrict__ b3,  // [4*NH]
    float* __restrict__ out,       // [nt, ns]
    int nt, int ns)
{
    // XCD-contiguous catchment map (verified R3: FETCH 64->8.3 MB, WRITE 32->4 MB)
    const int b    = blockIdx.x;
    const int s    = (b & 7) * (ns >> 3) + (b >> 3);
    const int tid  = threadIdx.x;
    const int lane = tid & 63;
    const bool crit = (tid < 64);          // wave 0 = critical, wave 1 = helper

    __shared__ float ytile[2][NH * YROW];  // [h][t] Hn tile, double-buffered (34.8 KB)
    __shared__ float scal[2][NH * 4];      // per-step {Tr,Ps,Pl,E}, double-buffered
    __shared__ float gqbuf[NH];            // go*ga per h (helper's reduction weights)

    // ---- static gates (both waves compute; parallel, off critical path) ----
    float wq[4];
    #pragma unroll
    for (int q = 0; q < 4; ++q) {
        const float4* row = reinterpret_cast<const float4*>(W3 + (size_t)(q * NH + lane) * NG);
        const float4* xr  = reinterpret_cast<const float4*>(xc + (size_t)s * NG);
        float a = 0.f;
        #pragma unroll
        for (int g = 0; g < NG / 4; ++g) {
            const float4 w  = row[g];
            const float4 xv = xr[g];
            a = fmaf(w.x, xv.x, a); a = fmaf(w.y, xv.y, a);
            a = fmaf(w.z, xv.z, a); a = fmaf(w.w, xv.w, a);
        }
        wq[q] = a + b3[q * NH + lane];
    }
    const float gm = expf(wq[0]) + 1.0f;               // melt gate (>0)
    const float ge = 1.0f / (1.0f + expf(-wq[1]));     // ET gate
    const float go = 1.0f / (1.0f + expf(-wq[2]));     // outflow gate
    float mx = wq[3];
    #pragma unroll
    for (int o = 32; o; o >>= 1) mx = fmaxf(mx, __shfl_xor(mx, o, 64));
    const float ex = expf(wq[3] - mx);
    float smx = ex;
    #pragma unroll
    for (int o = 32; o; o >>= 1) smx += __shfl_xor(smx, o, 64);
    const float ga = ex / smx;                         // softmax over h
    const float gq = go * ga;
    const float gk = 1.0f - go;

    if (!crit) gqbuf[lane] = gq;   // helper publishes/consumes its own copy (in-wave order)

    const int nchunk = (nt + NH - 1) / NH;

    // phase A: forcing float4 f -> {Tr,Ps,Pl,E} at dst[lane*4] (one ds_write_b128)
    #define PHASE_A(f, dst) { \
        const float P = (f).x, E = (f).y, T1 = (f).z, T2 = (f).w; \
        const float Ta  = 0.5f * (T1 + T2); \
        const float arg = fminf(1.f, fmaxf(-1.f, (T1 + T2) / (T2 - T1))); \
        const float aa  = fabsf(arg); \
        float p = fmaf(aa, -0.0012624911f, 0.0066700901f); \
        p = fmaf(aa, p, -0.0170881256f); p = fmaf(aa, p, 0.0308918810f); \
        p = fmaf(aa, p, -0.0501743046f); p = fmaf(aa, p, 0.0889789874f); \
        p = fmaf(aa, p, -0.2145988016f); p = fmaf(aa, p, 1.5707963050f); \
        const float rr0 = sqrtf(1.f - aa) * p; \
        const float ac  = (arg >= 0.f) ? rr0 : (3.14159265358979f - rr0); \
        const float rr  = 1.f - ac * (1.0f / 3.1415f);          /* module's PI */ \
        const float rP  = (T1 >= 0.f) ? 1.f : ((T2 <= 0.f) ? 0.f : rr); \
        float4 st; st.x = fmaxf(Ta, 0.f); st.y = (1.f - rP) * P; \
        st.z = rP * P;  st.w = E; \
        *reinterpret_cast<float4*>(&(dst)[lane * 4]) = st; \
    }

    #define LOAD8(dst, sp, j0) { \
        _Pragma("unroll") \
        for (int k = 0; k < 8; ++k) \
            dst[k] = *reinterpret_cast<const float4*>(&(sp)[((j0) + k) * 4]); \
    }

    // one recurrence step: 8 VALU (Hc carries Hn; H_prev = gk*Hc folded into fma)
    #define STEP(sc) { \
        const float M  = (sc).x * gm; \
        const float Sm = fminf(S, M); \
        S = (S - Sm) + (sc).y; \
        const float t2 = Sm + (sc).z; \
        const float t3 = fmaf(-(sc).w, ge, t2); \
        Hc = fmaxf(fmaf(gk, Hc, t3), 0.f); \
    }

    if (!crit) {   // phase A for chunk 0
        const int tp = min(lane, nt - 1);
        const float4 f = *reinterpret_cast<const float4*>(x + ((size_t)tp * ns + s) * 4);
        PHASE_A(f, scal[0])
    }
    __syncthreads();

    float S = 0.f, Hc = 0.f;

    #pragma unroll 1
    for (int c = 0; c < nchunk; ++c) {
        const int cnt = min(NH, nt - c * NH);
        if (crit) {
            const float* sp = scal[c & 1];
            float*       yb = &ytile[c & 1][lane * YROW];
            if (cnt == NH) {
                float4 sc[8], scn[8];
                LOAD8(sc, sp, 0)
                #pragma unroll
                for (int bb = 0; bb < 8; ++bb) {
                    if (bb < 7) LOAD8(scn, sp, (bb + 1) * 8)   // pipeline next batch
                    float yv[8];
                    #pragma unroll
                    for (int k = 0; k < 8; ++k) { STEP(sc[k]) yv[k] = Hc; }
                    *reinterpret_cast<float4*>(yb + bb * 8)     = make_float4(yv[0], yv[1], yv[2], yv[3]);
                    *reinterpret_cast<float4*>(yb + bb * 8 + 4) = make_float4(yv[4], yv[5], yv[6], yv[7]);
                    if (bb < 7) {
                        #pragma unroll
                        for (int k = 0; k < 8; ++k) sc[k] = scn[k];
                    }
                }
            } else {                       // tail chunk (40 steps for nt=1000)
                const int nb = cnt / 8;
                for (int bb = 0; bb < nb; ++bb) {
                    float4 sc[8];
                    LOAD8(sc, sp, bb * 8)
                    float yv[8];
                    #pragma unroll
                    for (int k = 0; k < 8; ++k) { STEP(sc[k]) yv[k] = Hc; }
                    *reinterpret_cast<float4*>(yb + bb * 8)     = make_float4(yv[0], yv[1], yv[2], yv[3]);
                    *reinterpret_cast<float4*>(yb + bb * 8 + 4) = make_float4(yv[4], yv[5], yv[6], yv[7]);
                }
                for (int j = nb * 8; j < cnt; ++j) {           // remainder (0 for nt=1000)
                    const float4 sc = *reinterpret_cast<const float4*>(&sp[j * 4]);
                    STEP(sc)
                    yb[j] = Hc;
                }
            }
        } else {
            // helper: (1) issue x prefetch for chunk c+1 (latency hides under phase C)
            const int tp = min((c + 1) * NH + lane, nt - 1);
            const float4 f = *reinterpret_cast<const float4*>(x + ((size_t)tp * ns + s) * 4);
            // (2) phase C: reduce chunk c-1 (always a full chunk when c>=1)
            if (c >= 1) {
                const float* yr = ytile[(c - 1) & 1];
                float z0 = 0.f, z1 = 0.f, z2 = 0.f, z3 = 0.f;
                #pragma unroll
                for (int h = 0; h < NH; h += 4) {
                    z0 = fmaf(gqbuf[h + 0], yr[(h + 0) * YROW + lane], z0);
                    z1 = fmaf(gqbuf[h + 1], yr[(h + 1) * YROW + lane], z1);
                    z2 = fmaf(gqbuf[h + 2], yr[(h + 2) * YROW + lane], z2);
                    z3 = fmaf(gqbuf[h + 3], yr[(h + 3) * YROW + lane], z3);
                }
                out[(size_t)((c - 1) * NH + lane) * ns + s] = (z0 + z1) + (z2 + z3);
            }
            // (3) phase A for chunk c+1 (harmless overwrite when c+1 == nchunk)
            PHASE_A(f, scal[(c + 1) & 1])
        }
        __syncthreads();
    }

    // epilogue: helper reduces the final chunk
    if (!crit) {
        const int c   = nchunk - 1;
        const int cnt = nt - c * NH;
        const float* yr = ytile[c & 1];
        float z0 = 0.f, z1 = 0.f, z2 = 0.f, z3 = 0.f;
        #pragma unroll
        for (int h = 0; h < NH; h += 4) {
            z0 = fmaf(gqbuf[h + 0], yr[(h + 0) * YROW + lane], z0);
            z1 = fmaf(gqbuf[h + 1], yr[(h + 1) * YROW + lane], z1);
            z2 = fmaf(gqbuf[h + 2], yr[(h + 2) * YROW + lane], z2);
            z3 = fmaf(gqbuf[h + 3], yr[(h + 3) * YROW + lane], z3);
        }
        if (lane < cnt)
            out[(size_t)(c * NH + lane) * ns + s] = (z0 + z1) + (z2 + z3);
    }
    #undef PHASE_A
    #undef LOAD8
    #undef STEP
}

extern "C" void kernel_launch(void* const* d_in, const int* in_sizes, int n_in,
                              void* d_out, int out_size, void* d_ws, size_t ws_size,
                              hipStream_t stream) {
    const float* x  = (const float*)d_in[0];
    const float* xc = (const float*)d_in[1];
    const float* W3 = (const float*)d_in[2];
    const float* b3 = (const float*)d_in[3];
    float* out = (float*)d_out;

    const int nh = in_sizes[3] / 4;            // 64
    const int ng = in_sizes[2] / (4 * nh);     // 32
    const int ns = in_sizes[1] / ng;           // 1024
    const int nt = in_sizes[0] / (ns * 4);     // 1000

    waternet_kernel<<<dim3(ns), dim3(128), 0, stream>>>(x, xc, W3, b3, out, nt, ns);
}